// Round 6
// baseline (209.592 us; speedup 1.0000x reference)
//
#include <hip/hip_runtime.h>
#include <hip/hip_bf16.h>

typedef __bf16 bf16_t;
typedef __bf16 bf16x8 __attribute__((ext_vector_type(8)));
typedef __bf16 bf16x4 __attribute__((ext_vector_type(4)));
typedef float f32x4 __attribute__((ext_vector_type(4)));
typedef short short4v __attribute__((ext_vector_type(4)));

#define SEQ_T 2048
#define DMODEL 2048
#define NQH 16
#define NKVH 4
#define HDIM 128

__device__ __forceinline__ f32x4 mfma16x16x32(bf16x8 a, bf16x8 b, f32x4 c) {
  return __builtin_amdgcn_mfma_f32_16x16x32_bf16(a, b, c, 0, 0, 0);
}
__device__ __forceinline__ f32x4 mfma16x16x16(bf16x4 a, bf16x4 b, f32x4 c) {
  return __builtin_amdgcn_mfma_f32_16x16x16bf16_1k(
      __builtin_bit_cast(short4v, a), __builtin_bit_cast(short4v, b), c, 0, 0, 0);
}

typedef __attribute__((address_space(3))) void lds_void_t;
typedef __attribute__((address_space(1))) const void gbl_void_t;
__device__ __forceinline__ void gload_lds16(const bf16_t* g, bf16_t* l) {
  __builtin_amdgcn_global_load_lds((gbl_void_t*)g, (lds_void_t*)l, 16, 0, 0);
}
__device__ __forceinline__ void BAR() {
  asm volatile("" ::: "memory");
  __builtin_amdgcn_s_barrier();
  asm volatile("" ::: "memory");
}

// ---------------- cast f32 -> bf16, 8 elems/thread ----------------
__global__ __launch_bounds__(256) void cast_kernel(const float* __restrict__ src,
                                                   bf16_t* __restrict__ dst, int n8) {
  int idx = blockIdx.x * 256 + threadIdx.x;
  if (idx >= n8) return;
  const float4* s = reinterpret_cast<const float4*>(src) + (size_t)idx * 2;
  float4 a = s[0], b = s[1];
  bf16x8 r = {(bf16_t)a.x, (bf16_t)a.y, (bf16_t)a.z, (bf16_t)a.w,
              (bf16_t)b.x, (bf16_t)b.y, (bf16_t)b.z, (bf16_t)b.w};
  reinterpret_cast<bf16x8*>(dst)[idx] = r;
}

// ---------------- RoPE cos/sin table [T][64] (cos, sin) ----------------
__global__ __launch_bounds__(256) void sincos_kernel(float2* __restrict__ tab) {
  int idx = blockIdx.x * 256 + threadIdx.x;  // 2048*64
  int t = idx >> 6, i = idx & 63;
  float inv = powf(10000.0f, -(float)i * (1.0f / 64.0f));
  float ang = (float)t * inv;
  float s, c;
  sincosf(ang, &s, &c);
  tab[idx] = make_float2(c, s);
}

// ---------------- 8-phase 256xBN GEMM: C[m,n] = sum_k A[m,k]*W[n,k] ----------------
// BM=256, BK=64, 8 waves (2M x 4N). Double-buffered LDS, 4 phases per K-tile:
// {ds_read quadrant | issue 1 half-tile prefetch -> raw barrier -> setprio+16 MFMA
// -> barrier}. Counted vmcnt(2) once per K-tile (phase 0) -- loads stay in flight
// across barriers. XOR-swizzled LDS (chunk ^ row&7), pre-swizzled global source.
// MODE 0 (BN=256): QKV epilogue, RoPE fused on Q/K; V transposed + kv-permuted.
// MODE 1 (BN=128): f32 C row-major [M][2048].
template <int MODE, int BN>
__global__ __launch_bounds__(512, 2) void gemm8p(const bf16_t* __restrict__ A,
                                                 const bf16_t* __restrict__ W,
                                                 bf16_t* __restrict__ q_out,
                                                 bf16_t* __restrict__ k_out,
                                                 bf16_t* __restrict__ v_out,
                                                 float* __restrict__ c_out,
                                                 const float2* __restrict__ tab) {
  constexpr int K = 2048;
  constexpr int NT = K / 64;                  // K-tiles
  constexpr int NTX = (MODE == 0) ? (3072 / BN) : (2048 / BN);
  constexpr int WN = BN / 4;                  // wave n-extent
  constexpr int NF = WN / 16;                 // n-frags per wave
  constexpr int NFH = NF / 2;                 // n-frags per phase
  constexpr int NH = 2 + BN / 128;            // half-tiles per K-tile
  const int nwg = gridDim.x;
  const int cpx = nwg >> 3;
  const int id = ((int)blockIdx.x & 7) * cpx + ((int)blockIdx.x >> 3);
  const int m0 = (id / NTX) * 256, n0 = (id % NTX) * BN;
  const int tid = threadIdx.x;
  const int lane = tid & 63, w = tid >> 6;
  const int wr = w >> 2, wc = w & 3;
  const int l15 = lane & 15, g = lane >> 4;
  __shared__ bf16_t smem[2][(256 + BN) * 64];
  f32x4 acc[8][NF] = {};
  bf16x8 af[4][2], bfr[NFH][2];

  auto ISSUE_HALF = [&](int tt, int h) {
    const int k0 = tt * 64;
    bf16_t* base = &smem[tt & 1][0] + ((h < 2) ? h * (128 * 64) : (256 + (h - 2) * 128) * 64);
    const bf16_t* src = (h < 2) ? (A + (size_t)(m0 + h * 128) * K)
                                : (W + (size_t)(n0 + (h - 2) * 128) * K);
#pragma unroll
    for (int i = 0; i < 2; i++) {
      const int rl = i * 64 + (tid >> 3);
      gload_lds16(src + (size_t)rl * K + k0 + (((tid & 7) ^ (rl & 7)) << 3),
                  base + (i * 64 + w * 8) * 64);
    }
  };
  auto RDA = [&](const bf16_t* Ab, int qm) {
#pragma unroll
    for (int fi = 0; fi < 4; fi++) {
      const int row = wr * 128 + qm * 64 + fi * 16 + l15;
#pragma unroll
      for (int ksl = 0; ksl < 2; ksl++)
        af[fi][ksl] = *reinterpret_cast<const bf16x8*>(
            Ab + row * 64 + ((((ksl << 2) + g) ^ (row & 7)) << 3));
    }
  };
  auto RDB = [&](const bf16_t* Bb, int qn) {
#pragma unroll
    for (int fj = 0; fj < NFH; fj++) {
      const int row = wc * WN + qn * (WN / 2) + fj * 16 + l15;
#pragma unroll
      for (int ksl = 0; ksl < 2; ksl++)
        bfr[fj][ksl] = *reinterpret_cast<const bf16x8*>(
            Bb + row * 64 + ((((ksl << 2) + g) ^ (row & 7)) << 3));
    }
  };

#define MMPH(QM, QN)                                                          \
  do {                                                                        \
    __builtin_amdgcn_s_setprio(1);                                            \
    _Pragma("unroll") for (int fi = 0; fi < 4; fi++)                          \
        _Pragma("unroll") for (int fj = 0; fj < NFH; fj++)                    \
            _Pragma("unroll") for (int ksl = 0; ksl < 2; ksl++)               \
                acc[(QM)*4 + fi][(QN)*NFH + fj] = mfma16x16x32(               \
                    af[fi][ksl], bfr[fj][ksl], acc[(QM)*4 + fi][(QN)*NFH + fj]); \
    __builtin_amdgcn_s_setprio(0);                                            \
  } while (0)

  // prologue: stage tile 0
#pragma unroll
  for (int h = 0; h < NH; h++) ISSUE_HALF(0, h);

  for (int t = 0; t < NT; t++) {
    const bf16_t* Ab = &smem[t & 1][0];
    const bf16_t* Bb = Ab + 256 * 64;
    // ---- phase 0: gate tile t, prefetch h0(t+1) ----
    if (t + 1 < NT) {
      ISSUE_HALF(t + 1, 0);
      asm volatile("s_waitcnt vmcnt(2)" ::: "memory");
    } else {
      asm volatile("s_waitcnt vmcnt(0)" ::: "memory");
    }
    BAR();
    RDA(Ab, 0);
    RDB(Bb, 0);
    MMPH(0, 0);
    BAR();
    // ---- phase 1 ----
    RDB(Bb, 1);
    if (t + 1 < NT) ISSUE_HALF(t + 1, 1);
    BAR();
    MMPH(0, 1);
    BAR();
    // ---- phase 2 ----
    RDA(Ab, 1);
    if (t + 1 < NT) ISSUE_HALF(t + 1, 2);
    BAR();
    MMPH(1, 1);
    BAR();
    // ---- phase 3 ----
    RDB(Bb, 0);
    if (t + 1 < NT && NH > 3) ISSUE_HALF(t + 1, 3);
    BAR();
    MMPH(1, 0);
    BAR();
  }
#undef MMPH

  if (MODE == 0) {
#pragma unroll
    for (int fm = 0; fm < 8; fm++) {
      const int r0 = m0 + wr * 128 + fm * 16 + (g << 2);
      const int bb = r0 >> 11;
      const int tt = r0 & 2047;
#pragma unroll
      for (int fn = 0; fn < NF; fn++) {
        const int col = n0 + wc * WN + fn * 16 + l15;
        const f32x4 v = acc[fm][fn];
        if (col < 2048) {  // Q region, RoPE fused
          const int dd = col & 127;
          const float2* tp = tab + (size_t)tt * 64 + (dd >> 1);
          bf16_t* dst = q_out + (((size_t)(bb * NQH + (col >> 7)) * SEQ_T + tt) * HDIM + dd);
#pragma unroll
          for (int i = 0; i < 4; i++) {
            float me = v[i];
            float ot = __shfl_xor(me, 1);
            float2 cs = tp[(size_t)i * 64];
            float r = (dd & 1) ? (me * cs.x + ot * cs.y) : (me * cs.x - ot * cs.y);
            dst[(size_t)i * HDIM] = (bf16_t)r;
          }
        } else if (col < 2560) {  // K region, RoPE fused
          const int dd = col & 127;
          const float2* tp = tab + (size_t)tt * 64 + (dd >> 1);
          bf16_t* dst = k_out + (((size_t)(bb * NKVH + ((col - 2048) >> 7)) * SEQ_T + tt) * HDIM + dd);
#pragma unroll
          for (int i = 0; i < 4; i++) {
            float me = v[i];
            float ot = __shfl_xor(me, 1);
            float2 cs = tp[(size_t)i * 64];
            float r = (dd & 1) ? (me * cs.x + ot * cs.y) : (me * cs.x - ot * cs.y);
            dst[(size_t)i * HDIM] = (bf16_t)r;
          }
        } else {  // V region -> transposed [B,KVh,128,T'] with kv-permutation
          const int vc = col - 2560;
          const int hh = vc >> 7, dd = vc & 127;
          const int tp64 = (tt & ~63) | (((tt >> 2) & 3) << 4) | (((tt >> 4) & 3) << 2);
          bf16x4 pk = {(bf16_t)v[0], (bf16_t)v[1], (bf16_t)v[2], (bf16_t)v[3]};
          *reinterpret_cast<bf16x4*>(v_out + (((size_t)(bb * NKVH + hh) * HDIM + dd) * SEQ_T + tp64)) = pk;
        }
      }
    }
  } else {
#pragma unroll
    for (int fm = 0; fm < 8; fm++) {
      const int r0 = m0 + wr * 128 + fm * 16 + (g << 2);
#pragma unroll
      for (int fn = 0; fn < NF; fn++) {
        const int col = n0 + wc * WN + fn * 16 + l15;
#pragma unroll
        for (int i = 0; i < 4; i++) c_out[(size_t)(r0 + i) * 2048 + col] = acc[fm][fn][i];
      }
    }
  }
}

// ---------------- Flash attention (causal GQA) ----------------
// Wave-split paired q-tiles: waves 0-3 own heavy q-tile jH=15-p (4 waves x 32
// q-rows = 128), waves 4-7 own light q-tile jL=p. KV stream staged ONCE
// (double-buffered, prefetch before compute); each wave covers 32 q-rows as
// two 16-q fragment groups (A/B) so every LDS K/V fragment read feeds 2x MFMAs
// -> halves the LDS-read critical path (the measured bottleneck).
// Swapped QK^T -> per-lane softmax; T13 defer-max; kscale folded into exp2 fma;
// mask skipped on fully-unmasked tiles; T5 setprio around MFMA clusters.
__global__ __launch_bounds__(512, 2) void attn_kernel(const bf16_t* __restrict__ Qb,
                                                      const bf16_t* __restrict__ Kb,
                                                      const bf16_t* __restrict__ Vt,
                                                      bf16_t* __restrict__ AO) {
  const int bh = blockIdx.x;
  const int b = bh >> 4, h = bh & 15, kvh = h >> 2;
  const int p = blockIdx.y;  // 0..7
  const int tid = threadIdx.x;
  const int lane = tid & 63, w = tid >> 6;
  const int tsel = w >> 2;           // 0 = heavy tile, 1 = light tile
  const int wq = w & 3;
  const int jT = tsel ? p : (15 - p);
  const int q0t = jT * 128;
  const bf16_t* Qp = Qb + (size_t)(b * NQH + h) * SEQ_T * HDIM;
  const bf16_t* Kp = Kb + (size_t)(b * NKVH + kvh) * SEQ_T * HDIM;
  const bf16_t* Vp = Vt + (size_t)(b * NKVH + kvh) * HDIM * SEQ_T;
  __shared__ bf16_t smem[2][16384];  // per buf: Ks [64][128] | Vs [128][64]
  const int l15 = lane & 15, g = lane >> 4;
  const int qrA = q0t + wq * 32 + l15;  // group A q-row; group B = +16
  bf16x8 qfA[4], qfB[4];
#pragma unroll
  for (int c = 0; c < 4; c++) {
    qfA[c] = *reinterpret_cast<const bf16x8*>(Qp + (size_t)qrA * HDIM + c * 32 + (g << 3));
    qfB[c] = *reinterpret_cast<const bf16x8*>(Qp + (size_t)(qrA + 16) * HDIM + c * 32 + (g << 3));
  }
  f32x4 oA[8] = {}, oB[8] = {};
  float mA = -1e30f, lA = 0.0f, mB = -1e30f, lB = 0.0f;
  const float kscale = 0.08838834764831845f * 1.4426950408889634f;  // 1/sqrt(128)*log2e
  const int wmax = q0t + wq * 32 + 31;     // wave active bound (max q row)
  const int ntiles = 2 * (15 - p) + 2;     // heavy-tile staged count (>= light need)
  const int kR0 = w * 4 + (lane >> 4);     // K stage row (+ cc*32)
  const int kG = lane & 15;
  const int vR0 = w * 8 + (lane >> 3);     // V stage row (+ cc*64)
  const int vG = lane & 7;

  auto STAGE = [&](int it, int buf) {
    const int kv0s = it * 64;
    bf16_t* Ks = smem[buf];
    bf16_t* Vs = smem[buf] + 8192;
#pragma unroll
    for (int cc = 0; cc < 2; cc++) {
      const int krow = cc * 32 + kR0;
      gload_lds16(Kp + (size_t)(kv0s + krow) * HDIM + ((kG ^ (krow & 7)) << 3),
                  Ks + (cc * 32 + w * 4) * 128);
      const int vrow = cc * 64 + vR0;
      gload_lds16(Vp + (size_t)vrow * SEQ_T + kv0s + ((vG ^ (vrow & 7)) << 3),
                  Vs + (cc * 64 + w * 8) * 64);
    }
  };

  STAGE(0, 0);
  __syncthreads();  // drains vmcnt(0)
  for (int it = 0; it < ntiles; it++) {
    const int buf = it & 1;
    if (it + 1 < ntiles) STAGE(it + 1, buf ^ 1);  // prefetch flies under compute
    const int kv0 = it * 64;
    const bf16_t* Ks = smem[buf];
    const bf16_t* Vs = smem[buf] + 8192;
    if (kv0 <= wmax) {
      float svA[16], svB[16];
      const bool noMask = (kv0 + 63 <= q0t + wq * 32);
      // S^T = K * Q^T for both 16-q groups, sharing every kf read
      __builtin_amdgcn_s_setprio(1);
#pragma unroll
      for (int ksub = 0; ksub < 4; ksub++) {
        f32x4 sa = {}, sb = {};
        const int krow = ksub * 16 + l15;
#pragma unroll
        for (int ch = 0; ch < 4; ch++) {
          bf16x8 kf = *reinterpret_cast<const bf16x8*>(
              Ks + krow * 128 + ((((ch << 2) + g) ^ (krow & 7)) << 3));
          sa = mfma16x16x32(kf, qfA[ch], sa);
          sb = mfma16x16x32(kf, qfB[ch], sb);
        }
        if (noMask) {
#pragma unroll
          for (int i = 0; i < 4; i++) { svA[ksub * 4 + i] = sa[i]; svB[ksub * 4 + i] = sb[i]; }
        } else {
          const int dltA = qrA - kv0 - ksub * 16 - (g << 2);
#pragma unroll
          for (int i = 0; i < 4; i++) {
            svA[ksub * 4 + i] = (i <= dltA) ? sa[i] : -3e38f;
            svB[ksub * 4 + i] = (i <= dltA + 16) ? sb[i] : -3e38f;
          }
        }
      }
      __builtin_amdgcn_s_setprio(0);
      // online softmax per group (raw-domain max; scaled via fma at exp2)
      float tmA = svA[0], tmB = svB[0];
#pragma unroll
      for (int j = 1; j < 16; j++) { tmA = fmaxf(tmA, svA[j]); tmB = fmaxf(tmB, svB[j]); }
      tmA = fmaxf(tmA, __shfl_xor(tmA, 16, 64));
      tmA = fmaxf(tmA, __shfl_xor(tmA, 32, 64));
      tmB = fmaxf(tmB, __shfl_xor(tmB, 16, 64));
      tmB = fmaxf(tmB, __shfl_xor(tmB, 32, 64));
      tmA *= kscale;
      tmB *= kscale;
      if (!__all(tmA <= mA + 8.0f)) {  // T13 defer-max
        const float mnew = fmaxf(mA, tmA);
        const float alpha = exp2f(mA - mnew);
        mA = mnew;
        lA *= alpha;
#pragma unroll
        for (int dt = 0; dt < 8; dt++) oA[dt] *= alpha;
      }
      if (!__all(tmB <= mB + 8.0f)) {
        const float mnew = fmaxf(mB, tmB);
        const float alpha = exp2f(mB - mnew);
        mB = mnew;
        lB *= alpha;
#pragma unroll
        for (int dt = 0; dt < 8; dt++) oB[dt] *= alpha;
      }
      float rsA = 0.0f, rsB = 0.0f;
#pragma unroll
      for (int j = 0; j < 16; j++) {
        svA[j] = exp2f(__builtin_fmaf(svA[j], kscale, -mA));
        rsA += svA[j];
        svB[j] = exp2f(__builtin_fmaf(svB[j], kscale, -mB));
        rsB += svB[j];
      }
      rsA += __shfl_xor(rsA, 16, 64);
      rsA += __shfl_xor(rsA, 32, 64);
      rsB += __shfl_xor(rsB, 16, 64);
      rsB += __shfl_xor(rsB, 32, 64);
      lA += rsA;
      lB += rsB;
      bf16x4 pbA[4], pbB[4];
#pragma unroll
      for (int ksub = 0; ksub < 4; ksub++) {
        bf16x4 ta = {(bf16_t)svA[ksub * 4], (bf16_t)svA[ksub * 4 + 1],
                     (bf16_t)svA[ksub * 4 + 2], (bf16_t)svA[ksub * 4 + 3]};
        pbA[ksub] = ta;
        bf16x4 tb = {(bf16_t)svB[ksub * 4], (bf16_t)svB[ksub * 4 + 1],
                     (bf16_t)svB[ksub * 4 + 2], (bf16_t)svB[ksub * 4 + 3]};
        pbB[ksub] = tb;
      }
      // O^T += V^T * P^T for both groups, sharing every vv read
      __builtin_amdgcn_s_setprio(1);
#pragma unroll
      for (int dt = 0; dt < 8; dt++) {
        const int vrow = dt * 16 + l15;
#pragma unroll
        for (int s = 0; s < 2; s++) {
          bf16x8 vv = *reinterpret_cast<const bf16x8*>(
              Vs + vrow * 64 + (((2 * g + s) ^ (vrow & 7)) << 3));
          bf16x4 v0 = {vv[0], vv[1], vv[2], vv[3]};
          bf16x4 v1 = {vv[4], vv[5], vv[6], vv[7]};
          oA[dt] = mfma16x16x16(v0, pbA[2 * s], oA[dt]);
          oA[dt] = mfma16x16x16(v1, pbA[2 * s + 1], oA[dt]);
          oB[dt] = mfma16x16x16(v0, pbB[2 * s], oB[dt]);
          oB[dt] = mfma16x16x16(v1, pbB[2 * s + 1], oB[dt]);
        }
      }
      __builtin_amdgcn_s_setprio(0);
    }
    __syncthreads();  // next tile's stage complete; all waves done with buf
  }
  // epilogue: per-wave LDS slice [32 q][128 d] then coalesced b128 out
  const float liA = 1.0f / lA, liB = 1.0f / lB;
  bf16_t* os = &smem[0][0] + w * 4096;
#pragma unroll
  for (int dt = 0; dt < 8; dt++) {
    bf16x4 pa = {(bf16_t)(oA[dt][0] * liA), (bf16_t)(oA[dt][1] * liA),
                 (bf16_t)(oA[dt][2] * liA), (bf16_t)(oA[dt][3] * liA)};
    *reinterpret_cast<bf16x4*>(os + l15 * 128 + dt * 16 + (g << 2)) = pa;
    bf16x4 pb2 = {(bf16_t)(oB[dt][0] * liB), (bf16_t)(oB[dt][1] * liB),
                  (bf16_t)(oB[dt][2] * liB), (bf16_t)(oB[dt][3] * liB)};
    *reinterpret_cast<bf16x4*>(os + (l15 + 16) * 128 + dt * 16 + (g << 2)) = pb2;
  }
  const size_t rowb = (size_t)b * SEQ_T + q0t + wq * 32;
#pragma unroll
  for (int itr = 0; itr < 8; itr++) {
    const int row = itr * 4 + (lane >> 4);
    *reinterpret_cast<bf16x8*>(AO + (rowb + row) * DMODEL + h * HDIM + l15 * 8) =
        *reinterpret_cast<const bf16x8*>(os + row * 128 + l15 * 8);
  }
}

extern "C" void kernel_launch(void* const* d_in, const int* in_sizes, int n_in,
                              void* d_out, int out_size, void* d_ws, size_t ws_size,
                              hipStream_t stream) {
  const float* x = (const float*)d_in[0];
  const float* Wq = (const float*)d_in[1];
  const float* Wk = (const float*)d_in[2];
  const float* Wv = (const float*)d_in[3];
  const float* Wo = (const float*)d_in[4];
  float* out = (float*)d_out;
  char* ws = (char*)d_ws;
  bf16_t* xb = (bf16_t*)(ws);                         // [4096][2048]        16 MB
  bf16_t* Wqkvb = (bf16_t*)(ws + 16777216);           // [3072][2048]        12 MB
  bf16_t* Wob = (bf16_t*)(ws + 29360128);             // [2048][2048]         8 MB
  bf16_t* Qb = (bf16_t*)(ws + 37748736);              // [2][16][2048][128]  16 MB
  bf16_t* Kb = (bf16_t*)(ws + 54525952);              // [2][4][2048][128]    4 MB
  bf16_t* Vt = (bf16_t*)(ws + 58720256);              // [2][4][128][2048]    4 MB (kv-permuted)
  bf16_t* AO = (bf16_t*)(ws + 62914560);              // [4096][2048]        16 MB
  float2* tab = (float2*)(ws + 79691776);             // [2048][64]           1 MB

  cast_kernel<<<4096, 256, 0, stream>>>(x, xb, 1048576);
  cast_kernel<<<2048, 256, 0, stream>>>(Wq, Wqkvb, 524288);
  cast_kernel<<<512, 256, 0, stream>>>(Wk, Wqkvb + (size_t)2048 * 2048, 131072);
  cast_kernel<<<512, 256, 0, stream>>>(Wv, Wqkvb + (size_t)2560 * 2048, 131072);
  cast_kernel<<<2048, 256, 0, stream>>>(Wo, Wob, 524288);
  sincos_kernel<<<512, 256, 0, stream>>>(tab);
  gemm8p<0, 256><<<192, 512, 0, stream>>>(xb, Wqkvb, Qb, Kb, Vt, nullptr, tab);
  attn_kernel<<<dim3(32, 8), 512, 0, stream>>>(Qb, Kb, Vt, AO);
  gemm8p<1, 128><<<256, 512, 0, stream>>>(AO, Wob, nullptr, nullptr, nullptr, out, nullptr);
}

// Round 7
// 203.665 us; speedup vs baseline: 1.0291x; 1.0291x over previous
//
#include <hip/hip_runtime.h>
#include <hip/hip_bf16.h>

typedef __bf16 bf16_t;
typedef __bf16 bf16x8 __attribute__((ext_vector_type(8)));
typedef __bf16 bf16x4 __attribute__((ext_vector_type(4)));
typedef float f32x4 __attribute__((ext_vector_type(4)));
typedef short short4v __attribute__((ext_vector_type(4)));

#define SEQ_T 2048
#define DMODEL 2048
#define NQH 16
#define NKVH 4
#define HDIM 128

__device__ __forceinline__ f32x4 mfma16x16x32(bf16x8 a, bf16x8 b, f32x4 c) {
  return __builtin_amdgcn_mfma_f32_16x16x32_bf16(a, b, c, 0, 0, 0);
}
__device__ __forceinline__ f32x4 mfma16x16x16(bf16x4 a, bf16x4 b, f32x4 c) {
  return __builtin_amdgcn_mfma_f32_16x16x16bf16_1k(
      __builtin_bit_cast(short4v, a), __builtin_bit_cast(short4v, b), c, 0, 0, 0);
}

typedef __attribute__((address_space(3))) void lds_void_t;
typedef __attribute__((address_space(1))) const void gbl_void_t;
__device__ __forceinline__ void gload_lds16(const bf16_t* g, bf16_t* l) {
  __builtin_amdgcn_global_load_lds((gbl_void_t*)g, (lds_void_t*)l, 16, 0, 0);
}
__device__ __forceinline__ void BAR() {
  asm volatile("" ::: "memory");
  __builtin_amdgcn_s_barrier();
  asm volatile("" ::: "memory");
}

// ---------------- cast f32 -> bf16, 8 elems/thread ----------------
__global__ __launch_bounds__(256) void cast_kernel(const float* __restrict__ src,
                                                   bf16_t* __restrict__ dst, int n8) {
  int idx = blockIdx.x * 256 + threadIdx.x;
  if (idx >= n8) return;
  const float4* s = reinterpret_cast<const float4*>(src) + (size_t)idx * 2;
  float4 a = s[0], b = s[1];
  bf16x8 r = {(bf16_t)a.x, (bf16_t)a.y, (bf16_t)a.z, (bf16_t)a.w,
              (bf16_t)b.x, (bf16_t)b.y, (bf16_t)b.z, (bf16_t)b.w};
  reinterpret_cast<bf16x8*>(dst)[idx] = r;
}

// ---------------- RoPE cos/sin table [T][64] (cos, sin) ----------------
__global__ __launch_bounds__(256) void sincos_kernel(float2* __restrict__ tab) {
  int idx = blockIdx.x * 256 + threadIdx.x;  // 2048*64
  int t = idx >> 6, i = idx & 63;
  float inv = powf(10000.0f, -(float)i * (1.0f / 64.0f));
  float ang = (float)t * inv;
  float s, c;
  sincosf(ang, &s, &c);
  tab[idx] = make_float2(c, s);
}

// ---------------- 8-phase 256xBN GEMM: C[m,n] = sum_k A[m,k]*W[n,k] ----------------
// BM=256, BK=64, 8 waves (2M x 4N). Double-buffered LDS, 4 phases per K-tile:
// {ds_read quadrant | issue 1 half-tile prefetch -> raw barrier -> setprio+16 MFMA
// -> barrier}. Counted vmcnt(2) once per K-tile (phase 0) -- loads stay in flight
// across barriers. XOR-swizzled LDS (chunk ^ row&7), pre-swizzled global source.
// MODE 0 (BN=256): QKV epilogue, RoPE fused on Q/K; V transposed + kv-permuted.
// MODE 1 (BN=128): f32 C row-major [M][2048].
template <int MODE, int BN>
__global__ __launch_bounds__(512, 2) void gemm8p(const bf16_t* __restrict__ A,
                                                 const bf16_t* __restrict__ W,
                                                 bf16_t* __restrict__ q_out,
                                                 bf16_t* __restrict__ k_out,
                                                 bf16_t* __restrict__ v_out,
                                                 float* __restrict__ c_out,
                                                 const float2* __restrict__ tab) {
  constexpr int K = 2048;
  constexpr int NT = K / 64;                  // K-tiles
  constexpr int NTX = (MODE == 0) ? (3072 / BN) : (2048 / BN);
  constexpr int WN = BN / 4;                  // wave n-extent
  constexpr int NF = WN / 16;                 // n-frags per wave
  constexpr int NFH = NF / 2;                 // n-frags per phase
  constexpr int NH = 2 + BN / 128;            // half-tiles per K-tile
  const int nwg = gridDim.x;
  const int cpx = nwg >> 3;
  const int id = ((int)blockIdx.x & 7) * cpx + ((int)blockIdx.x >> 3);
  const int m0 = (id / NTX) * 256, n0 = (id % NTX) * BN;
  const int tid = threadIdx.x;
  const int lane = tid & 63, w = tid >> 6;
  const int wr = w >> 2, wc = w & 3;
  const int l15 = lane & 15, g = lane >> 4;
  __shared__ bf16_t smem[2][(256 + BN) * 64];
  f32x4 acc[8][NF] = {};
  bf16x8 af[4][2], bfr[NFH][2];

  auto ISSUE_HALF = [&](int tt, int h) {
    const int k0 = tt * 64;
    bf16_t* base = &smem[tt & 1][0] + ((h < 2) ? h * (128 * 64) : (256 + (h - 2) * 128) * 64);
    const bf16_t* src = (h < 2) ? (A + (size_t)(m0 + h * 128) * K)
                                : (W + (size_t)(n0 + (h - 2) * 128) * K);
#pragma unroll
    for (int i = 0; i < 2; i++) {
      const int rl = i * 64 + (tid >> 3);
      gload_lds16(src + (size_t)rl * K + k0 + (((tid & 7) ^ (rl & 7)) << 3),
                  base + (i * 64 + w * 8) * 64);
    }
  };
  auto RDA = [&](const bf16_t* Ab, int qm) {
#pragma unroll
    for (int fi = 0; fi < 4; fi++) {
      const int row = wr * 128 + qm * 64 + fi * 16 + l15;
#pragma unroll
      for (int ksl = 0; ksl < 2; ksl++)
        af[fi][ksl] = *reinterpret_cast<const bf16x8*>(
            Ab + row * 64 + ((((ksl << 2) + g) ^ (row & 7)) << 3));
    }
  };
  auto RDB = [&](const bf16_t* Bb, int qn) {
#pragma unroll
    for (int fj = 0; fj < NFH; fj++) {
      const int row = wc * WN + qn * (WN / 2) + fj * 16 + l15;
#pragma unroll
      for (int ksl = 0; ksl < 2; ksl++)
        bfr[fj][ksl] = *reinterpret_cast<const bf16x8*>(
            Bb + row * 64 + ((((ksl << 2) + g) ^ (row & 7)) << 3));
    }
  };

#define MMPH(QM, QN)                                                          \
  do {                                                                        \
    __builtin_amdgcn_s_setprio(1);                                            \
    _Pragma("unroll") for (int fi = 0; fi < 4; fi++)                          \
        _Pragma("unroll") for (int fj = 0; fj < NFH; fj++)                    \
            _Pragma("unroll") for (int ksl = 0; ksl < 2; ksl++)               \
                acc[(QM)*4 + fi][(QN)*NFH + fj] = mfma16x16x32(               \
                    af[fi][ksl], bfr[fj][ksl], acc[(QM)*4 + fi][(QN)*NFH + fj]); \
    __builtin_amdgcn_s_setprio(0);                                            \
  } while (0)

  // prologue: stage tile 0
#pragma unroll
  for (int h = 0; h < NH; h++) ISSUE_HALF(0, h);

  for (int t = 0; t < NT; t++) {
    const bf16_t* Ab = &smem[t & 1][0];
    const bf16_t* Bb = Ab + 256 * 64;
    // ---- phase 0: gate tile t, prefetch h0(t+1) ----
    if (t + 1 < NT) {
      ISSUE_HALF(t + 1, 0);
      asm volatile("s_waitcnt vmcnt(2)" ::: "memory");
    } else {
      asm volatile("s_waitcnt vmcnt(0)" ::: "memory");
    }
    BAR();
    RDA(Ab, 0);
    RDB(Bb, 0);
    MMPH(0, 0);
    BAR();
    // ---- phase 1 ----
    RDB(Bb, 1);
    if (t + 1 < NT) ISSUE_HALF(t + 1, 1);
    BAR();
    MMPH(0, 1);
    BAR();
    // ---- phase 2 ----
    RDA(Ab, 1);
    if (t + 1 < NT) ISSUE_HALF(t + 1, 2);
    BAR();
    MMPH(1, 1);
    BAR();
    // ---- phase 3 ----
    RDB(Bb, 0);
    if (t + 1 < NT && NH > 3) ISSUE_HALF(t + 1, 3);
    BAR();
    MMPH(1, 0);
    BAR();
  }
#undef MMPH

  if (MODE == 0) {
#pragma unroll
    for (int fm = 0; fm < 8; fm++) {
      const int r0 = m0 + wr * 128 + fm * 16 + (g << 2);
      const int bb = r0 >> 11;
      const int tt = r0 & 2047;
#pragma unroll
      for (int fn = 0; fn < NF; fn++) {
        const int col = n0 + wc * WN + fn * 16 + l15;
        const f32x4 v = acc[fm][fn];
        if (col < 2048) {  // Q region, RoPE fused
          const int dd = col & 127;
          const float2* tp = tab + (size_t)tt * 64 + (dd >> 1);
          bf16_t* dst = q_out + (((size_t)(bb * NQH + (col >> 7)) * SEQ_T + tt) * HDIM + dd);
#pragma unroll
          for (int i = 0; i < 4; i++) {
            float me = v[i];
            float ot = __shfl_xor(me, 1);
            float2 cs = tp[(size_t)i * 64];
            float r = (dd & 1) ? (me * cs.x + ot * cs.y) : (me * cs.x - ot * cs.y);
            dst[(size_t)i * HDIM] = (bf16_t)r;
          }
        } else if (col < 2560) {  // K region, RoPE fused
          const int dd = col & 127;
          const float2* tp = tab + (size_t)tt * 64 + (dd >> 1);
          bf16_t* dst = k_out + (((size_t)(bb * NKVH + ((col - 2048) >> 7)) * SEQ_T + tt) * HDIM + dd);
#pragma unroll
          for (int i = 0; i < 4; i++) {
            float me = v[i];
            float ot = __shfl_xor(me, 1);
            float2 cs = tp[(size_t)i * 64];
            float r = (dd & 1) ? (me * cs.x + ot * cs.y) : (me * cs.x - ot * cs.y);
            dst[(size_t)i * HDIM] = (bf16_t)r;
          }
        } else {  // V region -> transposed [B,KVh,128,T'] with kv-permutation
          const int vc = col - 2560;
          const int hh = vc >> 7, dd = vc & 127;
          const int tp64 = (tt & ~63) | (((tt >> 2) & 3) << 4) | (((tt >> 4) & 3) << 2);
          bf16x4 pk = {(bf16_t)v[0], (bf16_t)v[1], (bf16_t)v[2], (bf16_t)v[3]};
          *reinterpret_cast<bf16x4*>(v_out + (((size_t)(bb * NKVH + hh) * HDIM + dd) * SEQ_T + tp64)) = pk;
        }
      }
    }
  } else {
#pragma unroll
    for (int fm = 0; fm < 8; fm++) {
      const int r0 = m0 + wr * 128 + fm * 16 + (g << 2);
#pragma unroll
      for (int fn = 0; fn < NF; fn++) {
        const int col = n0 + wc * WN + fn * 16 + l15;
#pragma unroll
        for (int i = 0; i < 4; i++) c_out[(size_t)(r0 + i) * 2048 + col] = acc[fm][fn][i];
      }
    }
  }
}

// ---------------- Flash attention (causal GQA) ----------------
// Balanced + shared: per wave, group A = 16 rows of HEAVY q-tile (jH=15-p),
// group B = 16 rows of LIGHT q-tile (jL=p). All 8 waves cover both tiles
// (R5 balance: 34 group-units/wave over 32 iters); when B is active the
// K/V fragment reads are shared between groups (R6 sharing). B active =>
// kv0 < q0L+128 <= q0H => A unmasked in the shared path. A-only iterations
// run a lean single-group path with standard masking.
// KV staged once per iter via gload_lds (double-buffered, prefetch-first).
// Swapped QK^T -> per-lane softmax; T13 defer-max; kscale folded into exp2 fma.
__global__ __launch_bounds__(512, 2) void attn_kernel(const bf16_t* __restrict__ Qb,
                                                      const bf16_t* __restrict__ Kb,
                                                      const bf16_t* __restrict__ Vt,
                                                      bf16_t* __restrict__ AO) {
  const int bh = blockIdx.x;
  const int b = bh >> 4, h = bh & 15, kvh = h >> 2;
  const int p = blockIdx.y;  // 0..7
  const int jH = 15 - p, jL = p;
  const int q0H = jH * 128, q0L = jL * 128;
  const int tid = threadIdx.x;
  const int lane = tid & 63, w = tid >> 6;
  const bf16_t* Qp = Qb + (size_t)(b * NQH + h) * SEQ_T * HDIM;
  const bf16_t* Kp = Kb + (size_t)(b * NKVH + kvh) * SEQ_T * HDIM;
  const bf16_t* Vp = Vt + (size_t)(b * NKVH + kvh) * HDIM * SEQ_T;
  __shared__ bf16_t smem[2][16384];  // per buf: Ks [64][128] | Vs [128][64]
  const int l15 = lane & 15, g = lane >> 4;
  const int qrA = q0H + w * 16 + l15;  // heavy-tile q-row
  const int qrB = q0L + w * 16 + l15;  // light-tile q-row
  bf16x8 qfA[4], qfB[4];
#pragma unroll
  for (int c = 0; c < 4; c++) {
    qfA[c] = *reinterpret_cast<const bf16x8*>(Qp + (size_t)qrA * HDIM + c * 32 + (g << 3));
    qfB[c] = *reinterpret_cast<const bf16x8*>(Qp + (size_t)qrB * HDIM + c * 32 + (g << 3));
  }
  f32x4 oA[8] = {}, oB[8] = {};
  float mA = -1e30f, lA = 0.0f, mB = -1e30f, lB = 0.0f;
  const float kscale = 0.08838834764831845f * 1.4426950408889634f;  // 1/sqrt(128)*log2e
  const int wmaxA = q0H + w * 16 + 15;
  const int wmaxB = q0L + w * 16 + 15;
  const int ntiles = 2 * jH + 2;
  const int kR0 = w * 4 + (lane >> 4);  // K stage row (+ cc*32)
  const int kG = lane & 15;
  const int vR0 = w * 8 + (lane >> 3);  // V stage row (+ cc*64)
  const int vG = lane & 7;

  auto STAGE = [&](int it, int buf) {
    const int kv0s = it * 64;
    bf16_t* Ks = smem[buf];
    bf16_t* Vs = smem[buf] + 8192;
#pragma unroll
    for (int cc = 0; cc < 2; cc++) {
      const int krow = cc * 32 + kR0;
      gload_lds16(Kp + (size_t)(kv0s + krow) * HDIM + ((kG ^ (krow & 7)) << 3),
                  Ks + (cc * 32 + w * 4) * 128);
      const int vrow = cc * 64 + vR0;
      gload_lds16(Vp + (size_t)vrow * SEQ_T + kv0s + ((vG ^ (vrow & 7)) << 3),
                  Vs + (cc * 64 + w * 8) * 64);
    }
  };

  // softmax + P-pack for one group (sv in raw score domain)
  auto SOFTMAX = [&](float* sv, float& m, float& l, f32x4* o, bf16x4* pb) {
    float tm = sv[0];
#pragma unroll
    for (int j = 1; j < 16; j++) tm = fmaxf(tm, sv[j]);
    tm = fmaxf(tm, __shfl_xor(tm, 16, 64));
    tm = fmaxf(tm, __shfl_xor(tm, 32, 64));
    tm *= kscale;
    if (!__all(tm <= m + 8.0f)) {  // T13 defer-max
      const float mnew = fmaxf(m, tm);
      const float alpha = exp2f(m - mnew);
      m = mnew;
      l *= alpha;
#pragma unroll
      for (int dt = 0; dt < 8; dt++) o[dt] *= alpha;
    }
    float rs = 0.0f;
#pragma unroll
    for (int j = 0; j < 16; j++) {
      sv[j] = exp2f(__builtin_fmaf(sv[j], kscale, -m));
      rs += sv[j];
    }
    rs += __shfl_xor(rs, 16, 64);
    rs += __shfl_xor(rs, 32, 64);
    l += rs;
#pragma unroll
    for (int ksub = 0; ksub < 4; ksub++) {
      bf16x4 t = {(bf16_t)sv[ksub * 4], (bf16_t)sv[ksub * 4 + 1],
                  (bf16_t)sv[ksub * 4 + 2], (bf16_t)sv[ksub * 4 + 3]};
      pb[ksub] = t;
    }
  };

  // single-group compute (A-only path), with masking
  auto COMPUTE1 = [&](const bf16_t* Ks, const bf16_t* Vs, int kv0) {
    float sv[16];
    const bool noMask = (kv0 + 63 <= q0H + w * 16);
    __builtin_amdgcn_s_setprio(1);
#pragma unroll
    for (int ksub = 0; ksub < 4; ksub++) {
      f32x4 sa = {};
      const int krow = ksub * 16 + l15;
#pragma unroll
      for (int ch = 0; ch < 4; ch++) {
        bf16x8 kf = *reinterpret_cast<const bf16x8*>(
            Ks + krow * 128 + ((((ch << 2) + g) ^ (krow & 7)) << 3));
        sa = mfma16x16x32(kf, qfA[ch], sa);
      }
      if (noMask) {
#pragma unroll
        for (int i = 0; i < 4; i++) sv[ksub * 4 + i] = sa[i];
      } else {
        const int dlt = qrA - kv0 - ksub * 16 - (g << 2);
#pragma unroll
        for (int i = 0; i < 4; i++) sv[ksub * 4 + i] = (i <= dlt) ? sa[i] : -3e38f;
      }
    }
    __builtin_amdgcn_s_setprio(0);
    bf16x4 pb[4];
    SOFTMAX(sv, mA, lA, oA, pb);
    __builtin_amdgcn_s_setprio(1);
#pragma unroll
    for (int dt = 0; dt < 8; dt++) {
      const int vrow = dt * 16 + l15;
#pragma unroll
      for (int s = 0; s < 2; s++) {
        bf16x8 vv = *reinterpret_cast<const bf16x8*>(
            Vs + vrow * 64 + (((2 * g + s) ^ (vrow & 7)) << 3));
        bf16x4 v0 = {vv[0], vv[1], vv[2], vv[3]};
        bf16x4 v1 = {vv[4], vv[5], vv[6], vv[7]};
        oA[dt] = mfma16x16x16(v0, pb[2 * s], oA[dt]);
        oA[dt] = mfma16x16x16(v1, pb[2 * s + 1], oA[dt]);
      }
    }
    __builtin_amdgcn_s_setprio(0);
  };

  // shared-read compute: A (unmasked here) + B (masked near its diagonal)
  auto COMPUTE2 = [&](const bf16_t* Ks, const bf16_t* Vs, int kv0) {
    float svA[16], svB[16];
    const bool noMaskB = (kv0 + 63 <= q0L + w * 16);
    __builtin_amdgcn_s_setprio(1);
#pragma unroll
    for (int ksub = 0; ksub < 4; ksub++) {
      f32x4 sa = {}, sb = {};
      const int krow = ksub * 16 + l15;
#pragma unroll
      for (int ch = 0; ch < 4; ch++) {
        bf16x8 kf = *reinterpret_cast<const bf16x8*>(
            Ks + krow * 128 + ((((ch << 2) + g) ^ (krow & 7)) << 3));
        sa = mfma16x16x32(kf, qfA[ch], sa);
        sb = mfma16x16x32(kf, qfB[ch], sb);
      }
#pragma unroll
      for (int i = 0; i < 4; i++) svA[ksub * 4 + i] = sa[i];
      if (noMaskB) {
#pragma unroll
        for (int i = 0; i < 4; i++) svB[ksub * 4 + i] = sb[i];
      } else {
        const int dltB = qrB - kv0 - ksub * 16 - (g << 2);
#pragma unroll
        for (int i = 0; i < 4; i++) svB[ksub * 4 + i] = (i <= dltB) ? sb[i] : -3e38f;
      }
    }
    __builtin_amdgcn_s_setprio(0);
    bf16x4 pbA[4], pbB[4];
    SOFTMAX(svA, mA, lA, oA, pbA);
    SOFTMAX(svB, mB, lB, oB, pbB);
    __builtin_amdgcn_s_setprio(1);
#pragma unroll
    for (int dt = 0; dt < 8; dt++) {
      const int vrow = dt * 16 + l15;
#pragma unroll
      for (int s = 0; s < 2; s++) {
        bf16x8 vv = *reinterpret_cast<const bf16x8*>(
            Vs + vrow * 64 + (((2 * g + s) ^ (vrow & 7)) << 3));
        bf16x4 v0 = {vv[0], vv[1], vv[2], vv[3]};
        bf16x4 v1 = {vv[4], vv[5], vv[6], vv[7]};
        oA[dt] = mfma16x16x16(v0, pbA[2 * s], oA[dt]);
        oA[dt] = mfma16x16x16(v1, pbA[2 * s + 1], oA[dt]);
        oB[dt] = mfma16x16x16(v0, pbB[2 * s], oB[dt]);
        oB[dt] = mfma16x16x16(v1, pbB[2 * s + 1], oB[dt]);
      }
    }
    __builtin_amdgcn_s_setprio(0);
  };

  STAGE(0, 0);
  __syncthreads();  // drains vmcnt(0)
  for (int it = 0; it < ntiles; it++) {
    const int buf = it & 1;
    if (it + 1 < ntiles) STAGE(it + 1, buf ^ 1);  // prefetch flies under compute
    const int kv0 = it * 64;
    const bf16_t* Ks = smem[buf];
    const bf16_t* Vs = smem[buf] + 8192;
    if (kv0 <= wmaxB) {
      COMPUTE2(Ks, Vs, kv0);  // B active => A active & unmasked
    } else if (kv0 <= wmaxA) {
      COMPUTE1(Ks, Vs, kv0);
    }
    __syncthreads();  // next tile's stage complete; all waves done with buf
  }
  // epilogue: per-wave LDS slice [16 q][128 d], then coalesced b128 out
  bf16_t* os = &smem[0][0] + w * 2048;
  auto EPI = [&](f32x4* o, float lsum, int q0) {
    const float linv = 1.0f / lsum;
#pragma unroll
    for (int dt = 0; dt < 8; dt++) {
      bf16x4 pk = {(bf16_t)(o[dt][0] * linv), (bf16_t)(o[dt][1] * linv),
                   (bf16_t)(o[dt][2] * linv), (bf16_t)(o[dt][3] * linv)};
      *reinterpret_cast<bf16x4*>(os + l15 * 128 + dt * 16 + (g << 2)) = pk;
    }
    const size_t rowb = (size_t)b * SEQ_T + q0 + w * 16;
#pragma unroll
    for (int kk = 0; kk < 4; kk++) {
      const int c = lane + kk * 64;
      const int q = c >> 4, gc = c & 15;
      *reinterpret_cast<bf16x8*>(AO + (rowb + q) * DMODEL + h * HDIM + gc * 8) =
          *reinterpret_cast<const bf16x8*>(os + q * 128 + gc * 8);
    }
  };
  EPI(oA, lA, q0H);
  EPI(oB, lB, q0L);
}

extern "C" void kernel_launch(void* const* d_in, const int* in_sizes, int n_in,
                              void* d_out, int out_size, void* d_ws, size_t ws_size,
                              hipStream_t stream) {
  const float* x = (const float*)d_in[0];
  const float* Wq = (const float*)d_in[1];
  const float* Wk = (const float*)d_in[2];
  const float* Wv = (const float*)d_in[3];
  const float* Wo = (const float*)d_in[4];
  float* out = (float*)d_out;
  char* ws = (char*)d_ws;
  bf16_t* xb = (bf16_t*)(ws);                         // [4096][2048]        16 MB
  bf16_t* Wqkvb = (bf16_t*)(ws + 16777216);           // [3072][2048]        12 MB
  bf16_t* Wob = (bf16_t*)(ws + 29360128);             // [2048][2048]         8 MB
  bf16_t* Qb = (bf16_t*)(ws + 37748736);              // [2][16][2048][128]  16 MB
  bf16_t* Kb = (bf16_t*)(ws + 54525952);              // [2][4][2048][128]    4 MB
  bf16_t* Vt = (bf16_t*)(ws + 58720256);              // [2][4][128][2048]    4 MB (kv-permuted)
  bf16_t* AO = (bf16_t*)(ws + 62914560);              // [4096][2048]        16 MB
  float2* tab = (float2*)(ws + 79691776);             // [2048][64]           1 MB

  cast_kernel<<<4096, 256, 0, stream>>>(x, xb, 1048576);
  cast_kernel<<<2048, 256, 0, stream>>>(Wq, Wqkvb, 524288);
  cast_kernel<<<512, 256, 0, stream>>>(Wk, Wqkvb + (size_t)2048 * 2048, 131072);
  cast_kernel<<<512, 256, 0, stream>>>(Wv, Wqkvb + (size_t)2560 * 2048, 131072);
  cast_kernel<<<2048, 256, 0, stream>>>(Wo, Wob, 524288);
  sincos_kernel<<<512, 256, 0, stream>>>(tab);
  gemm8p<0, 256><<<192, 512, 0, stream>>>(xb, Wqkvb, Qb, Kb, Vt, nullptr, tab);
  attn_kernel<<<dim3(32, 8), 512, 0, stream>>>(Qb, Kb, Vt, AO);
  gemm8p<1, 128><<<256, 512, 0, stream>>>(AO, Wob, nullptr, nullptr, nullptr, out, nullptr);
}